// Round 16
// baseline (100.069 us; speedup 1.0000x reference)
//
#include <hip/hip_runtime.h>
#include <math.h>

#define NQ 10
#define NL 3
#define PI_F 3.14159265358979f
#define TPB 256   // 4 waves/block; ONE batch element per wave

typedef _Float16 f16x8 __attribute__((ext_vector_type(8)));
typedef _Float16 h2t  __attribute__((ext_vector_type(2)));
typedef float    f32x4 __attribute__((ext_vector_type(4)));

// Compiler memory barrier + LDS drain (R13-proven safety discipline).
#define LDSFENCE asm volatile("s_waitcnt lgkmcnt(0)" ::: "memory")

// Composed CNOT-ring permutation (GF(2)-linear), compile-time only.
__host__ __device__ constexpr int cnot_chain_ce(int j) {
    for (int i = NQ - 1; i >= 0; --i) {
        int tq = (i + 1) % NQ;
        j ^= ((j >> (NQ - 1 - i)) & 1) << (NQ - 1 - tq);
    }
    return j;
}

// S-tier slot function: EXACTLY GF(2)-linear (pure XOR/shift, no carries).
// Bank images: GATH perm-constants {24,48,96,192,12} -> dim 5 -> conflict-free;
// STL {1,2,4,9,10,20} -> dim 5 -> 2-way; IST lane-bits -> dim 5 -> 2-way.
// Injective on [0,1024): recover m top-down bit by bit.
__host__ __device__ constexpr int sl_ce(int m) { return m ^ (m >> 3) ^ (m >> 5); }

__device__ __forceinline__ unsigned pkh(float r, float i) {
    return __builtin_bit_cast(unsigned, __builtin_amdgcn_cvt_pkrtz(r, i));
}

// Build a B-fragment (f16x8): element e = selected f16 half of dw[e].
// psel picks lo halves (re-plane lanes) or hi halves (im-plane lanes).
__device__ __forceinline__ f16x8 mkfrag(unsigned d0, unsigned d1, unsigned d2,
                                        unsigned d3, unsigned d4, unsigned d5,
                                        unsigned d6, unsigned d7, unsigned sel) {
    uint4 u;
    u.x = __builtin_amdgcn_perm(d1, d0, sel);
    u.y = __builtin_amdgcn_perm(d3, d2, sel);
    u.z = __builtin_amdgcn_perm(d5, d4, sel);
    u.w = __builtin_amdgcn_perm(d7, d6, sel);
    return __builtin_bit_cast(f16x8, u);
}

// lane-xor exchange for the final reduction: 1,2,4,8 DPP; 16 swizzle; 32 shfl
template<int MASK>
__device__ __forceinline__ unsigned lxu(unsigned v) {
    if constexpr (MASK == 1)
        return (unsigned)__builtin_amdgcn_update_dpp(0, (int)v, 0xB1, 0xF, 0xF, true);
    else if constexpr (MASK == 2)
        return (unsigned)__builtin_amdgcn_update_dpp(0, (int)v, 0x4E, 0xF, 0xF, true);
    else if constexpr (MASK == 4) {
        int a = __builtin_amdgcn_update_dpp(0, (int)v, 0x1B, 0xF, 0xF, true);
        return (unsigned)__builtin_amdgcn_update_dpp(0, a, 0x141, 0xF, 0xF, true);
    } else if constexpr (MASK == 8) {
        int a = __builtin_amdgcn_update_dpp(0, (int)v, 0x141, 0xF, 0xF, true);
        return (unsigned)__builtin_amdgcn_update_dpp(0, a, 0x140, 0xF, 0xF, true);
    } else if constexpr (MASK == 16)
        return (unsigned)__builtin_amdgcn_ds_swizzle((int)v, 0x401F);
    else
        return (unsigned)__shfl_xor((int)v, 32, 64);
}
#define WR1(v, M) v += __builtin_bit_cast(float, lxu<M>(__builtin_bit_cast(unsigned, v)));
#define WRED(v) { WR1(v,1) WR1(v,2) WR1(v,4) WR1(v,8) WR1(v,16) WR1(v,32) }

#define FORALL16(F) F(0) F(1) F(2) F(3) F(4) F(5) F(6) F(7) \
                    F(8) F(9) F(10) F(11) F(12) F(13) F(14) F(15)
#define FORALLQ(F) F(0) F(1) F(2) F(3) F(4) F(5) F(6) F(7) F(8) F(9)

// ============ prep: fused gate matrices -> MFMA A-fragments (R10-verified) ============
__global__ void vq_prep(const float* __restrict__ w, uint4* __restrict__ frag,
                        float* __restrict__ qcoef) {
    __shared__ float msh[NL * NQ][8];
    const int tid = threadIdx.x;
    if (tid < NL * NQ) {
        const float* wp = w + tid * 3;
        float sa = __sinf(wp[0]*0.5f), ca = __cosf(wp[0]*0.5f);
        float sb = __sinf(wp[1]*0.5f), cb = __cosf(wp[1]*0.5f);
        float sc = __sinf(wp[2]*0.5f), cc = __cosf(wp[2]*0.5f);
        float c00r = cb*ca,  c00i =  sa*sb;
        float c01r = -sb*ca, c01i = -cb*sa;
        float c10r =  sb*ca, c10i = -cb*sa;
        float c11r =  cb*ca, c11i = -sb*sa;
        float m[8];
        m[0] = cc*c00r + sc*c00i;  m[1] = cc*c00i - sc*c00r;
        m[2] = cc*c01r + sc*c01i;  m[3] = cc*c01i - sc*c01r;
        m[4] = cc*c10r - sc*c10i;  m[5] = cc*c10i + sc*c10r;
        m[6] = cc*c11r - sc*c11i;  m[7] = cc*c11i + sc*c11r;
#pragma unroll
        for (int j = 0; j < 8; ++j) msh[tid][j] = m[j];
        const int l = tid / NQ, q = tid % NQ;
        if (q < 2)
#pragma unroll
            for (int j = 0; j < 8; ++j) qcoef[(l*2 + q)*8 + j] = m[j];
    }
    __syncthreads();
    const int lane = tid & 63, wg = tid >> 6;
    const int mrow = lane & 15, quad = lane >> 4;
#pragma unroll 1
    for (int c = 0; c < 3; ++c) {
        const int id = c*4 + wg;            // id = l*4 + s*2 + v
        const int l = id >> 2, s = (id >> 1) & 1, v = id & 1;
        const int qb = s ? 2 : 6;
        unsigned pd[4];
#pragma unroll
        for (int d = 0; d < 4; ++d) {
            float hv[2];
#pragma unroll
            for (int h = 0; h < 2; ++h) {
                const int k = quad*8 + 2*d + h;
                const int col = k & 15;
                float er = 1.f, ei = 0.f;
#pragma unroll
                for (int p = 0; p < 4; ++p) {
                    const float* mm = msh[l*NQ + qb + p];
                    const int rb = (mrow >> (3-p)) & 1, cb2 = (col >> (3-p)) & 1;
                    const float gr = mm[(rb*2 + cb2)*2], gi = mm[(rb*2 + cb2)*2 + 1];
                    const float nr = er*gr - ei*gi, ni = er*gi + ei*gr;
                    er = nr; ei = ni;
                }
                hv[h] = (k < 16) ? (v ? ei : er) : (v ? er : -ei);
            }
            h2t hh; hh.x = (_Float16)hv[0]; hh.y = (_Float16)hv[1];
            pd[d] = __builtin_bit_cast(unsigned, hh);
        }
        frag[id*64 + lane] = make_uint4(pd[0], pd[1], pd[2], pd[3]);
    }
}

// ============ main kernel (R13 data semantics; new address encodings only) ============
// S  (inter-layer): value S[m] lives at sl(m) = m ^ (m>>3) ^ (m>>5).
//    Perm applied at GATH READ (R13-verified): reads sl(P(k)).
// S' (intra-layer): slot = 68*j' + 16*t_hi + (t_lo ^ (j'&7)).
// ALL LDS accesses scalar `unsigned` + LDSFENCE at every boundary (R13-proven).

#define DECLF(q) float f0_##q, f1_##q;
#define MKF(q) { float e_ = __expf(2.0f * xr[q]); \
    float h_ = (1.0f - 2.0f / (e_ + 1.0f)) * (PI_F * 0.5f); \
    f1_##q = __sinf(h_); f0_##q = __cosf(h_); }

// init: S0[m] at sl(m), m = 16*lane + J; sl(m) = sl(16*lane) ^ sl_ce(J)
#define IST(J) { float a_ = pr \
    * ((((J) >> 3) & 1) ? f1_6 : f0_6) * ((((J) >> 2) & 1) ? f1_7 : f0_7) \
    * ((((J) >> 1) & 1) ? f1_8 : f0_8) * (((J) & 1) ? f1_9 : f0_9); \
    P[baseI ^ sl_ce(J)] = pkh(a_, 0.0f); }

// stage-A gather, perm at read (R13-verified addressing, linear-folded slot):
// addr = sl(P(k)) = sl(PBv) ^ sl_ce(P(256b) ^ P(i)); k = 256b + 16n + 8q1 + i
#define LDA1(b,i) { constexpr int spc_ = \
        sl_ce(cnot_chain_ce((b)*256) ^ cnot_chain_ce(i)); \
    dw##i = P[LPBv ^ spc_]; }
#define GATH(b) LDA1(b,0) LDA1(b,1) LDA1(b,2) LDA1(b,3) LDA1(b,4) LDA1(b,5) LDA1(b,6) LDA1(b,7) \
    fr##b = mkfrag(dw0,dw1,dw2,dw3,dw4,dw5,dw6,dw7,psel);

// stage-A MFMA + store to S': element (j'=4quad+r, t_hi=b, t_lo=n) at
// 272quad + 68r + 16b + (n ^ (4q1+r)).  Banks: (n^r) bijective per quad-half -> free.
#define MMA_A(b) { \
    f32x4 cr_ = __builtin_amdgcn_mfma_f32_16x16x32_f16(aAr, fr##b, z4, 0, 0, 0); \
    f32x4 ci_ = __builtin_amdgcn_mfma_f32_16x16x32_f16(aAi, fr##b, z4, 0, 0, 0); \
    P[sAq + 16*(b)       +  nq_     ] = pkh(cr_.x, ci_.x); \
    P[sAq + 16*(b) +  68 + (nq_ ^ 1)] = pkh(cr_.y, ci_.y); \
    P[sAq + 16*(b) + 136 + (nq_ ^ 2)] = pkh(cr_.z, ci_.z); \
    P[sAq + 16*(b) + 204 + (nq_ ^ 3)] = pkh(cr_.w, ci_.w); }

// stage-B gather: element (j'=n, t_hi=b, t_lo=8q1+i) at gBq + 16b + (i ^ nu_).
// dw_i still holds row t_lo = 8q1+i (address-only swizzle).
#define GATB(b) { const int gb_ = gBq + 16*(b); \
    dw0 = P[gb_ + (0 ^ nu_)]; dw1 = P[gb_ + (1 ^ nu_)]; \
    dw2 = P[gb_ + (2 ^ nu_)]; dw3 = P[gb_ + (3 ^ nu_)]; \
    dw4 = P[gb_ + (4 ^ nu_)]; dw5 = P[gb_ + (5 ^ nu_)]; \
    dw6 = P[gb_ + (6 ^ nu_)]; dw7 = P[gb_ + (7 ^ nu_)]; \
    fr##b = mkfrag(dw0,dw1,dw2,dw3,dw4,dw5,dw6,dw7,psel); }

#define MMA_B(b) \
    car##b = __builtin_amdgcn_mfma_f32_16x16x32_f16(aBr, fr##b, z4, 0, 0, 0); \
    cai##b = __builtin_amdgcn_mfma_f32_16x16x32_f16(aBi, fr##b, z4, 0, 0, 0);

// complex 2x2 gate on C-accumulator block pair (f32)
#define CGATE(pa, pb, qp) { \
    const float g0_=(qp)[0], g1_=(qp)[1], g2_=(qp)[2], g3_=(qp)[3]; \
    const float g4_=(qp)[4], g5_=(qp)[5], g6_=(qp)[6], g7_=(qp)[7]; \
    f32x4 ar_ = car##pa, ai_ = cai##pa, br_ = car##pb, bi_ = cai##pb; \
    car##pa = g0_*ar_ - g1_*ai_ + g2_*br_ - g3_*bi_; \
    cai##pa = g0_*ai_ + g1_*ar_ + g2_*bi_ + g3_*br_; \
    car##pb = g4_*ar_ - g5_*ai_ + g6_*br_ - g7_*bi_; \
    cai##pb = g4_*ai_ + g5_*ar_ + g6_*bi_ + g7_*br_; }

// layer store to S, natural order (R13-verified semantics): S_new[k_out] at
// sl(k_out), k_out = 256b + 64quad + 16r + n; sl folds: LQ ^ sl_ce(256b+16r)
#define ST1(b, roff, comp) { \
    constexpr int sc_ = sl_ce(256*(b) + 16*(roff)); \
    P[LQ ^ sc_] = pkh(car##b.comp, cai##b.comp); }
#define STL(b) ST1(b,0,x) ST1(b,1,y) ST1(b,2,z) ST1(b,3,w)

#define ROD(b, r, comp) { const float p_ = car##b.comp*car##b.comp + cai##b.comp*cai##b.comp; \
    Sx += p_; \
    aq0 += ((b)&2) ? -p_ : p_;  aq1 += ((b)&1) ? -p_ : p_; \
    aq4 += ((r)&2) ? -p_ : p_;  aq5 += ((r)&1) ? -p_ : p_; }
#define ROB(b) ROD(b,0,x) ROD(b,1,y) ROD(b,2,z) ROD(b,3,w)

__global__ __launch_bounds__(TPB)
__attribute__((amdgpu_waves_per_eu(4, 4)))
void vq_main(const float* __restrict__ x, const uint4* __restrict__ frag,
             const float* __restrict__ qcoef, float* __restrict__ out) {
    __shared__ __align__(16) unsigned pl[4][1088];   // wave-private planes
    const int tid = threadIdx.x, wv = tid >> 6, lane = tid & 63;
    unsigned* P = pl[wv];
    const int elem = __builtin_amdgcn_readfirstlane(blockIdx.x * 4 + wv);
    const int n = lane & 15, quad = lane >> 4, q1 = quad & 1;
    const unsigned psel = (lane & 32) ? 0x07060302u : 0x05040100u;

    // perm addressing (R13-verified): P(k) = P(16n) ^ P(8q1) ^ P(256b) ^ P(i)
    int Pn = 0;
#pragma unroll
    for (int mm = 0; mm < 4; ++mm)
        Pn ^= ((n >> mm) & 1) ? cnot_chain_ce(16 << mm) : 0;
    const int PBv  = Pn ^ (q1 ? cnot_chain_ce(8) : 0);
    const int LPBv = sl_ce(PBv);              // linear-folded GATH base
    const int LQ   = sl_ce(64*quad + n);      // linear-folded STL base
    const int baseI = sl_ce(16*lane);         // linear-folded IST base
    const int sAq  = 272*quad;                // S' store base
    const int nq_  = n ^ (4*q1);              // S' store column swizzle part
    const int nu_  = n & 7;                   // S' read row swizzle part
    const int gBq  = 68*n + 8*q1;             // S' read base

    // ---- init: plain product state S0[m] at sl(m) (perm applied at GATH)
    const float* xr = x + elem * NQ;
    FORALLQ(DECLF)
    FORALLQ(MKF)
    {
        const float pr = (((lane>>5)&1) ? f1_0 : f0_0) * (((lane>>4)&1) ? f1_1 : f0_1)
                       * (((lane>>3)&1) ? f1_2 : f0_2) * (((lane>>2)&1) ? f1_3 : f0_3)
                       * (((lane>>1)&1) ? f1_4 : f0_4) * ((lane&1) ? f1_5 : f0_5);
        FORALL16(IST)
    }
    LDSFENCE;

    f32x4 car0, car1, car2, car3, cai0, cai1, cai2, cai3;
    const f32x4 z4 = {0.f, 0.f, 0.f, 0.f};

#pragma unroll 1
    for (int l = 0; l < NL; ++l) {
        const uint4* fp = frag + l*4*64;
        const f16x8 aAr = __builtin_bit_cast(f16x8, fp[lane]);
        const f16x8 aAi = __builtin_bit_cast(f16x8, fp[64 + lane]);
        const f16x8 aBr = __builtin_bit_cast(f16x8, fp[128 + lane]);
        const f16x8 aBi = __builtin_bit_cast(f16x8, fp[192 + lane]);
        const float* qc = qcoef + l*16;
        unsigned dw0, dw1, dw2, dw3, dw4, dw5, dw6, dw7;
        f16x8 fr0, fr1, fr2, fr3;

        // stage A: conflict-free gathers (perm at read), then MFMA + store into S'
        GATH(0) GATH(1) GATH(2) GATH(3)
        LDSFENCE;                          // S reads done before S' overwrites
        MMA_A(0) MMA_A(1) MMA_A(2) MMA_A(3)
        LDSFENCE;                          // S' stores done before S' reads

        // stage B: swizzled loads from S', MFMA, qubit-0/1 register gates
        GATB(0) GATB(1) GATB(2) GATB(3)
        LDSFENCE;                          // S' reads done before STL overwrites
        MMA_B(0) MMA_B(1) MMA_B(2) MMA_B(3)
        CGATE(0, 1, qc + 8)  CGATE(2, 3, qc + 8)   // qubit 1 (t_hi bit0)
        CGATE(0, 2, qc)      CGATE(1, 3, qc)       // qubit 0 (t_hi bit1)
        if (l < NL - 1) {
            STL(0) STL(1) STL(2) STL(3)            // natural-order store into S
            LDSFENCE;                      // S stores done before next GATH
        }
    }

    // ---- readout from C regs: k = (16b + 4quad + r)*16 + n
    float Sx = 0.f, aq0 = 0.f, aq1 = 0.f, aq4 = 0.f, aq5 = 0.f;
    ROB(0) ROB(1) ROB(2) ROB(3)
    float w2 = ((lane>>5)&1) ? -Sx : Sx;
    float w3 = ((lane>>4)&1) ? -Sx : Sx;
    float w6 = ((lane>>3)&1) ? -Sx : Sx;
    float w7 = ((lane>>2)&1) ? -Sx : Sx;
    float w8 = ((lane>>1)&1) ? -Sx : Sx;
    float w9 = (lane&1) ? -Sx : Sx;
    WRED(aq0) WRED(aq1) WRED(w2) WRED(w3) WRED(aq4)
    WRED(aq5) WRED(w6) WRED(w7) WRED(w8) WRED(w9)
    if (lane == 0) {
        float* op = out + elem * NQ;
        op[0] = aq0; op[1] = aq1; op[2] = w2; op[3] = w3; op[4] = aq4;
        op[5] = aq5; op[6] = w6; op[7] = w7; op[8] = w8; op[9] = w9;
    }
}

extern "C" void kernel_launch(void* const* d_in, const int* in_sizes, int n_in,
                              void* d_out, int out_size, void* d_ws, size_t ws_size,
                              hipStream_t stream) {
    const float* x = (const float*)d_in[0];   // (16384, 10) fp32
    const float* w = (const float*)d_in[1];   // (3, 10, 3) fp32
    float* out = (float*)d_out;               // (16384, 10) fp32
    uint4* frag = (uint4*)d_ws;               // 768 uint4 = 12 KB A-fragments
    float* qcoef = (float*)((char*)d_ws + 768 * sizeof(uint4));   // 48 floats
    const int B = in_sizes[0] / NQ;           // 16384
    vq_prep<<<dim3(1), dim3(TPB), 0, stream>>>(w, frag, qcoef);
    vq_main<<<dim3(B / 4), dim3(TPB), 0, stream>>>(x, frag, qcoef, out);
}